// Round 1
// baseline (86.253 us; speedup 1.0000x reference)
//
#include <hip/hip_runtime.h>
#include <hip/hip_bf16.h>

// Problem constants (from setup_inputs): bs=16, nq=64, ngt=32, D=4096, ncls=33
#define BS   16
#define NQ   64
#define NGT  32
#define DIM  4096
#define NCLS 33

// ---------------------------------------------------------------------------
// Kernel 1: cost matrix C[b][q][g] = sum_d |heat[b,q,d]-gt[b,g,d]| + (1 - prob[b,q,label[b,g]])
// One block per (b,q). Heat row staged in LDS; 4 waves x 8 gts each.
// ---------------------------------------------------------------------------
__global__ __launch_bounds__(256) void cost_kernel(
    const float* __restrict__ prob, const int* __restrict__ label,
    const float* __restrict__ heat, const float* __restrict__ gt,
    float* __restrict__ C)
{
    __shared__ float hrow[DIM];
    const int b = blockIdx.x >> 6;
    const int q = blockIdx.x & 63;

    const float4* hp = (const float4*)(heat + ((size_t)b * NQ + q) * DIM);
    float4* hl = (float4*)hrow;
    for (int i = threadIdx.x; i < DIM / 4; i += 256) hl[i] = hp[i];
    __syncthreads();

    const int wave = threadIdx.x >> 6;
    const int lane = threadIdx.x & 63;

    for (int g = wave; g < NGT; g += 4) {
        const float4* gp = (const float4*)(gt + ((size_t)b * NGT + g) * DIM);
        float s = 0.f;
        for (int i = lane; i < DIM / 4; i += 64) {
            float4 gv = gp[i];
            float4 hv = hl[i];
            s += fabsf(hv.x - gv.x) + fabsf(hv.y - gv.y) +
                 fabsf(hv.z - gv.z) + fabsf(hv.w - gv.w);
        }
        // 64-lane sum reduce
        for (int off = 32; off; off >>= 1) s += __shfl_xor(s, off);
        if (lane == 0) {
            int lb = label[b * NGT + g];
            float cp = 1.0f - prob[((size_t)b * NQ + q) * NCLS + lb];
            C[((size_t)b * NQ + q) * NGT + g] = s + cp;
        }
    }
}

// ---------------------------------------------------------------------------
// Kernel 2: exact rectangular LSAP (Jonker-Volgenant shortest augmenting path),
// one wave (64 lanes) per batch. Solves on cost^T: rows = gt (n=32), cols = q (m=64).
// Lane j owns column j: v, shortest, path, SC, row4col in registers.
// Lane i (i<32) owns row i: u, col4row in registers (accessed via __shfl).
// Cost matrix in LDS: cost[g*64 + q].
// ---------------------------------------------------------------------------
__global__ __launch_bounds__(64) void lsap_kernel(
    const float* __restrict__ C, int* __restrict__ out)
{
    __shared__ float cost[NGT * NQ];
    const int b = blockIdx.x;
    const int lane = threadIdx.x;  // 0..63

    // Transposed load: cost[g][q] = C[b][q][g]
    const float* Cb = C + (size_t)b * NQ * NGT;
    for (int idx = lane; idx < NQ * NGT; idx += 64) {
        int q = idx >> 5;      // /32
        int g = idx & 31;      // %32
        cost[g * 64 + q] = Cb[idx];
    }
    __syncthreads();

    const float INF = __builtin_inff();

    float v = 0.f;        // dual for column `lane`
    float u_reg = 0.f;    // dual for row `lane` (valid lane<32)
    int c4r = -1;         // col4row for row `lane` (valid lane<32)
    int r4c = -1;         // row4col for column `lane`

    for (int cur = 0; cur < NGT; ++cur) {
        // ---- Dijkstra shortest augmenting path from row `cur` ----
        unsigned SRmask = 0;      // wave-uniform visited-row bitmask
        float shortest = INF;     // per column
        int pathv = 0;            // per column
        bool SC = false;          // per column
        float minVal = 0.f;       // uniform
        int i = cur;              // uniform current row
        int sink = -1;            // uniform

        while (sink < 0) {
            SRmask |= (1u << i);
            float ui = __shfl(u_reg, i);
            float lowest = minVal + cost[i * 64 + lane] - ui - v;
            if (!SC && lowest < shortest) { shortest = lowest; pathv = i; }
            float masked = SC ? INF : shortest;
            // exact min reduce
            float mv = masked;
            for (int off = 32; off; off >>= 1) mv = fminf(mv, __shfl_xor(mv, off));
            // first lane achieving the min (matches jnp.argmin tie-break)
            unsigned long long ball = __ballot(masked == mv);
            int j = __ffsll((unsigned long long)ball) - 1;
            minVal = mv;
            if (lane == j) SC = true;
            int r = __shfl(r4c, j);
            if (r < 0) sink = j;
            else       i = r;
        }

        // ---- dual updates (use pre-augment col4row) ----
        if (lane == cur) u_reg += minVal;
        {
            // for rows in SR (except cur): u[i] += minVal - shortest[col4row[i]]
            float shc = __shfl(shortest, c4r & 63);  // own col4row, clamped for shuffle
            bool rowupd = (lane < NGT) && (lane != cur) && ((SRmask >> lane) & 1u);
            if (rowupd) u_reg += minVal - shc;
        }
        if (SC) v -= minVal - shortest;

        // ---- augment back from sink ----
        int j = sink;
        while (true) {
            int ii = __shfl(pathv, j);   // path[j], uniform
            if (lane == j) r4c = ii;
            int prev = __shfl(c4r, ii);  // old col4row[ii], uniform
            if (lane == ii) c4r = j;
            if (ii == cur) break;
            j = prev;
        }
    }

    // ---- argsort(col4row) and write (rows, cols) ----
    // col4row values are distinct in [0,64). rank = #{g' : c4r[g'] < c4r[g]}
    int c = c4r;
    int rank = 0;
    for (int t = 0; t < NGT; ++t) {
        int ct = __shfl(c4r, t);
        rank += (ct < c) ? 1 : 0;
    }
    if (lane < NGT) {
        out[b * NGT + rank] = c;                    // rows: matched query idx, ascending
        out[BS * NGT + b * NGT + rank] = lane;      // cols: corresponding gt idx
    }
}

extern "C" void kernel_launch(void* const* d_in, const int* in_sizes, int n_in,
                              void* d_out, int out_size, void* d_ws, size_t ws_size,
                              hipStream_t stream) {
    const float* prob  = (const float*)d_in[0];
    const int*   label = (const int*)d_in[1];
    const float* heat  = (const float*)d_in[2];
    const float* gt    = (const float*)d_in[3];
    int* out = (int*)d_out;
    float* C = (float*)d_ws;   // BS*NQ*NGT floats = 128 KiB

    cost_kernel<<<dim3(BS * NQ), dim3(256), 0, stream>>>(prob, label, heat, gt, C);
    lsap_kernel<<<dim3(BS), dim3(64), 0, stream>>>(C, out);
}

// Round 2
// 56.666 us; speedup vs baseline: 1.5221x; 1.5221x over previous
//
#include <hip/hip_runtime.h>
#include <hip/hip_bf16.h>

// Problem constants (from setup_inputs): bs=16, nq=64, ngt=32, D=4096, ncls=33
#define BS   16
#define NQ   64
#define NGT  32
#define DIM  4096
#define NCLS 33

// ---------------------------------------------------------------------------
// Kernel 1: cost matrix C[b][q][g] = sum_d |heat[b,q,d]-gt[b,g,d]| + (1 - prob[b,q,label[b,g]])
// One block per (b,q). Heat row staged in LDS.
// Each of 4 waves owns 8 gt rows, accumulated SIMULTANEOUSLY (8 independent
// global loads in flight per chunk iteration -> latency hiding without more waves).
// blockIdx decode b = idx & 15 puts every block of batch b on XCD b%8
// (hardware maps blockIdx -> XCD round-robin %8; 16 = 0 mod 8), so each XCD's
// L2 only holds gt/heat for 2 batches.
// ---------------------------------------------------------------------------
__global__ __launch_bounds__(256) void cost_kernel(
    const float* __restrict__ prob, const int* __restrict__ label,
    const float* __restrict__ heat, const float* __restrict__ gt,
    float* __restrict__ C)
{
    __shared__ float hrow[DIM];
    const int b = blockIdx.x & 15;
    const int q = blockIdx.x >> 4;

    const float4* hp = (const float4*)(heat + ((size_t)b * NQ + q) * DIM);
    float4* hl = (float4*)hrow;
    for (int i = threadIdx.x; i < DIM / 4; i += 256) hl[i] = hp[i];
    __syncthreads();

    const int wave = threadIdx.x >> 6;
    const int lane = threadIdx.x & 63;
    const int g0 = wave * 8;

    const float* gbase = gt + ((size_t)b * NGT + g0) * DIM;

    float acc[8];
    #pragma unroll
    for (int g = 0; g < 8; ++g) acc[g] = 0.f;

    for (int i = lane; i < DIM / 4; i += 64) {
        float4 hv = hl[i];
        #pragma unroll
        for (int g = 0; g < 8; ++g) {
            float4 gv = ((const float4*)(gbase + (size_t)g * DIM))[i];
            acc[g] += fabsf(hv.x - gv.x) + fabsf(hv.y - gv.y) +
                      fabsf(hv.z - gv.z) + fabsf(hv.w - gv.w);
        }
    }

    // 8 x 64-lane sum reductions; lane g keeps result for gt g0+g
    float myval = 0.f;
    #pragma unroll
    for (int g = 0; g < 8; ++g) {
        float s = acc[g];
        for (int off = 32; off; off >>= 1) s += __shfl_xor(s, off);
        if (lane == g) myval = s;
    }

    if (lane < 8) {
        int g = g0 + lane;
        int lb = label[b * NGT + g];
        float cp = 1.0f - prob[((size_t)b * NQ + q) * NCLS + lb];
        C[((size_t)b * NQ + q) * NGT + g] = myval + cp;
    }
}

// ---------------------------------------------------------------------------
// Kernel 2: exact rectangular LSAP (Jonker-Volgenant shortest augmenting path),
// one wave (64 lanes) per batch. Solves on cost^T: rows = gt (n=32), cols = q (m=64).
// Lane j owns column j: v, shortest, path, SC, row4col in registers.
// Lane i (i<32) owns row i: u, col4row in registers (accessed via __shfl).
// Cost matrix in LDS: cost[g*64 + q].
// ---------------------------------------------------------------------------
__global__ __launch_bounds__(64) void lsap_kernel(
    const float* __restrict__ C, int* __restrict__ out)
{
    __shared__ float cost[NGT * NQ];
    const int b = blockIdx.x;
    const int lane = threadIdx.x;  // 0..63

    // Transposed load: cost[g][q] = C[b][q][g]
    const float* Cb = C + (size_t)b * NQ * NGT;
    for (int idx = lane; idx < NQ * NGT; idx += 64) {
        int q = idx >> 5;      // /32
        int g = idx & 31;      // %32
        cost[g * 64 + q] = Cb[idx];
    }
    __syncthreads();

    const float INF = __builtin_inff();

    float v = 0.f;        // dual for column `lane`
    float u_reg = 0.f;    // dual for row `lane` (valid lane<32)
    int c4r = -1;         // col4row for row `lane` (valid lane<32)
    int r4c = -1;         // row4col for column `lane`

    for (int cur = 0; cur < NGT; ++cur) {
        // ---- Dijkstra shortest augmenting path from row `cur` ----
        unsigned SRmask = 0;      // wave-uniform visited-row bitmask
        float shortest = INF;     // per column
        int pathv = 0;            // per column
        bool SC = false;          // per column
        float minVal = 0.f;       // uniform
        int i = cur;              // uniform current row
        int sink = -1;            // uniform

        while (sink < 0) {
            SRmask |= (1u << i);
            float ui = __shfl(u_reg, i);
            float lowest = minVal + cost[i * 64 + lane] - ui - v;
            if (!SC && lowest < shortest) { shortest = lowest; pathv = i; }
            float masked = SC ? INF : shortest;
            // exact min reduce
            float mv = masked;
            for (int off = 32; off; off >>= 1) mv = fminf(mv, __shfl_xor(mv, off));
            // first lane achieving the min (matches jnp.argmin tie-break)
            unsigned long long ball = __ballot(masked == mv);
            int j = __ffsll((unsigned long long)ball) - 1;
            minVal = mv;
            if (lane == j) SC = true;
            int r = __shfl(r4c, j);
            if (r < 0) sink = j;
            else       i = r;
        }

        // ---- dual updates (use pre-augment col4row) ----
        if (lane == cur) u_reg += minVal;
        {
            // for rows in SR (except cur): u[i] += minVal - shortest[col4row[i]]
            float shc = __shfl(shortest, c4r & 63);  // own col4row, clamped for shuffle
            bool rowupd = (lane < NGT) && (lane != cur) && ((SRmask >> lane) & 1u);
            if (rowupd) u_reg += minVal - shc;
        }
        if (SC) v -= minVal - shortest;

        // ---- augment back from sink ----
        int j = sink;
        while (true) {
            int ii = __shfl(pathv, j);   // path[j], uniform
            if (lane == j) r4c = ii;
            int prev = __shfl(c4r, ii);  // old col4row[ii], uniform
            if (lane == ii) c4r = j;
            if (ii == cur) break;
            j = prev;
        }
    }

    // ---- argsort(col4row) and write (rows, cols) ----
    // col4row values are distinct in [0,64). rank = #{g' : c4r[g'] < c4r[g]}
    int c = c4r;
    int rank = 0;
    for (int t = 0; t < NGT; ++t) {
        int ct = __shfl(c4r, t);
        rank += (ct < c) ? 1 : 0;
    }
    if (lane < NGT) {
        out[b * NGT + rank] = c;                    // rows: matched query idx, ascending
        out[BS * NGT + b * NGT + rank] = lane;      // cols: corresponding gt idx
    }
}

extern "C" void kernel_launch(void* const* d_in, const int* in_sizes, int n_in,
                              void* d_out, int out_size, void* d_ws, size_t ws_size,
                              hipStream_t stream) {
    const float* prob  = (const float*)d_in[0];
    const int*   label = (const int*)d_in[1];
    const float* heat  = (const float*)d_in[2];
    const float* gt    = (const float*)d_in[3];
    int* out = (int*)d_out;
    float* C = (float*)d_ws;   // BS*NQ*NGT floats = 128 KiB

    cost_kernel<<<dim3(BS * NQ), dim3(256), 0, stream>>>(prob, label, heat, gt, C);
    lsap_kernel<<<dim3(BS), dim3(64), 0, stream>>>(C, out);
}

// Round 3
// 41.474 us; speedup vs baseline: 2.0797x; 1.3663x over previous
//
#include <hip/hip_runtime.h>
#include <hip/hip_bf16.h>

// Problem constants (from setup_inputs): bs=16, nq=64, ngt=32, D=4096, ncls=33
#define BS   16
#define NQ   64
#define NGT  32
#define DIM  4096
#define NCLS 33

#define QT      4              // heat rows per block
#define NCHUNK  4              // D split
#define CHUNK   (DIM / NCHUNK) // 1024

// ---------------------------------------------------------------------------
// Kernel 1: partial cost  Cp[c][b][q][g] = sum_{d in chunk c} |heat[b,q,d]-gt[b,g,d]|
// Block = (b, q-tile of 4, chunk). b = blockIdx&15 pins all blocks of a batch
// to XCD b%8 (working set/XCD: 2 batches' gt+heat = 3 MB < 4 MB L2).
// 4 waves x (8 gt x 4 q) register tile: 8 independent global loads in flight,
// each reused 4x from LDS heat rows. gt L2 traffic: 512 MB -> 128 MB.
// ---------------------------------------------------------------------------
__global__ __launch_bounds__(256) void cost_kernel(
    const float* __restrict__ heat, const float* __restrict__ gt,
    float* __restrict__ Cp)
{
    __shared__ float hrow[QT][CHUNK];
    const int bid  = blockIdx.x;        // 16*16*4 = 1024 blocks
    const int b    = bid & 15;
    const int rest = bid >> 4;          // 0..63
    const int qt   = rest & (NQ / QT - 1);  // 0..15
    const int c    = rest >> 4;         // 0..3
    const int q0   = qt * QT;

    const float* hbase = heat + ((size_t)(b * NQ + q0)) * DIM + c * CHUNK;
    for (int i = threadIdx.x; i < QT * CHUNK / 4; i += 256) {
        int r = i >> 8;        // / (CHUNK/4 = 256)
        int k = i & 255;
        ((float4*)hrow[r])[k] = ((const float4*)(hbase + (size_t)r * DIM))[k];
    }
    __syncthreads();

    const int wave = threadIdx.x >> 6;
    const int lane = threadIdx.x & 63;
    const int g0 = wave * 8;
    const float* gbase = gt + ((size_t)(b * NGT + g0)) * DIM + c * CHUNK;

    float acc[8][QT];
    #pragma unroll
    for (int g = 0; g < 8; ++g)
        #pragma unroll
        for (int q = 0; q < QT; ++q) acc[g][q] = 0.f;

    for (int i = lane; i < CHUNK / 4; i += 64) {   // 4 iterations
        float4 hv[QT];
        #pragma unroll
        for (int q = 0; q < QT; ++q) hv[q] = ((float4*)hrow[q])[i];
        #pragma unroll
        for (int g = 0; g < 8; ++g) {
            float4 gv = ((const float4*)(gbase + (size_t)g * DIM))[i];
            #pragma unroll
            for (int q = 0; q < QT; ++q) {
                acc[g][q] += fabsf(hv[q].x - gv.x) + fabsf(hv[q].y - gv.y) +
                             fabsf(hv[q].z - gv.z) + fabsf(hv[q].w - gv.w);
            }
        }
    }

    // Multi-value butterfly: reduce 32 values across 64 lanes in 33 shuffles.
    // After the loop, lane l (l<32) holds the total of value index l (= g*4+q).
    float r[32];
    #pragma unroll
    for (int k = 0; k < 32; ++k) r[k] = acc[k >> 2][k & 3];
    #pragma unroll
    for (int n = 32, m = 1; n > 1; n >>= 1, m <<= 1) {
        #pragma unroll
        for (int k = 0; k < 32; ++k) {      // only k < n/2 active
            if (k < n / 2) {
                float a  = r[2 * k], bb = r[2 * k + 1];
                bool  hi = (lane & m) != 0;
                float keep = hi ? bb : a;
                float send = hi ? a : bb;
                r[k] = keep + __shfl_xor(send, m);
            }
        }
    }
    float tot = r[0] + __shfl_xor(r[0], 32);
    if (lane < 32) {
        int gl = lane >> 2, ql = lane & 3;
        Cp[((size_t)((c * BS + b) * NQ + (q0 + ql))) * NGT + (g0 + gl)] = tot;
    }
}

// ---------------------------------------------------------------------------
// Helpers: DPP-based min (VALU pipe, ~2cy vs ds_swizzle ~30+cy) and readlane.
// ---------------------------------------------------------------------------
__device__ __forceinline__ float dppmin(float x, const int ctrl) {
    int t;
    switch (ctrl) {   // ctrl must be a literal for the builtin
        case 0xB1:  t = __builtin_amdgcn_update_dpp(0, __float_as_int(x), 0xB1,  0xf, 0xf, true); break;
        case 0x4E:  t = __builtin_amdgcn_update_dpp(0, __float_as_int(x), 0x4E,  0xf, 0xf, true); break;
        case 0x141: t = __builtin_amdgcn_update_dpp(0, __float_as_int(x), 0x141, 0xf, 0xf, true); break;
        default:    t = __builtin_amdgcn_update_dpp(0, __float_as_int(x), 0x140, 0xf, 0xf, true); break;
    }
    return fminf(x, __int_as_float(t));
}
__device__ __forceinline__ float rdlane_f(float x, int l) {
    return __int_as_float(__builtin_amdgcn_readlane(__float_as_int(x), l));
}

// ---------------------------------------------------------------------------
// Kernel 2: exact rectangular LSAP (Jonker-Volgenant), one wave per batch.
// Lane j owns column j (v, shortest, path, SC, row4col in registers);
// lane i<32 owns row i (u, col4row). Uniform-index cross-lane reads use
// v_readlane; the argmin uses a 4-stage DPP fmin tree (exact; tie-break by
// ballot+ffs matches jnp.argmin first-index semantics).
// ---------------------------------------------------------------------------
__global__ __launch_bounds__(64) void lsap_kernel(
    const float* __restrict__ Cp, const float* __restrict__ prob,
    const int* __restrict__ label, int* __restrict__ out)
{
    __shared__ float cost[NGT * NQ];
    const int b = blockIdx.x;
    const int lane = threadIdx.x;  // 0..63

    // cost[g][q] = sum_c Cp[c][b][q][g] + (1 - prob[b,q,label[b,g]])
    for (int idx = lane; idx < NQ * NGT; idx += 64) {
        int q = idx >> 5;      // 0..63
        int g = idx & 31;      // 0..31
        float ch = 0.f;
        #pragma unroll
        for (int c = 0; c < NCHUNK; ++c)
            ch += Cp[((size_t)((c * BS + b) * NQ + q)) * NGT + g];
        int lb = label[b * NGT + g];
        float cpr = 1.0f - prob[((size_t)b * NQ + q) * NCLS + lb];
        cost[g * 64 + q] = ch + cpr;
    }
    __syncthreads();

    const float INF = __builtin_inff();

    float v = 0.f;        // dual for column `lane`
    float u_reg = 0.f;    // dual for row `lane` (valid lane<32)
    int c4r = -1;         // col4row for row `lane` (valid lane<32)
    int r4c = -1;         // row4col for column `lane`

    for (int cur = 0; cur < NGT; ++cur) {
        // ---- Dijkstra shortest augmenting path from row `cur` ----
        unsigned SRmask = 0;
        float shortest = INF;
        int pathv = 0;
        bool SC = false;
        float minVal = 0.f;
        int i = cur;
        int sink = -1;

        while (sink < 0) {
            SRmask |= (1u << i);
            float ci = cost[(i << 6) + lane];          // ds_read, on critical path
            float ui = rdlane_f(u_reg, i);
            float lowest = minVal + ci - ui - v;
            if (!SC && lowest < shortest) { shortest = lowest; pathv = i; }
            float masked = SC ? INF : shortest;
            // exact min via DPP tree (per-16 mins) + 4 readlanes
            float x = masked;
            x = dppmin(x, 0xB1);    // xor 1
            x = dppmin(x, 0x4E);    // xor 2
            x = dppmin(x, 0x141);   // half-mirror -> min over 8
            x = dppmin(x, 0x140);   // mirror      -> min over 16
            float mv = rdlane_f(x, 0);
            mv = fminf(mv, rdlane_f(x, 16));
            mv = fminf(mv, rdlane_f(x, 32));
            mv = fminf(mv, rdlane_f(x, 48));
            unsigned long long ball = __ballot(masked == mv);
            int j = __ffsll(ball) - 1;                 // first-index tie-break
            minVal = mv;
            if (lane == j) SC = true;
            int r = __builtin_amdgcn_readlane(r4c, j);
            if (r < 0) sink = j;
            else       i = r;
        }

        // ---- dual updates (pre-augment col4row) ----
        if (lane == cur) u_reg += minVal;
        {
            float shc = __shfl(shortest, c4r & 63);    // per-lane index gather
            bool rowupd = (lane < NGT) && (lane != cur) && ((SRmask >> lane) & 1u);
            if (rowupd) u_reg += minVal - shc;
        }
        if (SC) v -= minVal - shortest;

        // ---- augment back from sink ----
        int j = sink;
        while (true) {
            int ii = __builtin_amdgcn_readlane(pathv, j);
            if (lane == j) r4c = ii;
            int prev = __builtin_amdgcn_readlane(c4r, ii);
            if (lane == ii) c4r = j;
            if (ii == cur) break;
            j = prev;
        }
    }

    // ---- argsort(col4row) and write (rows, cols) ----
    int c = c4r;
    int rank = 0;
    for (int t = 0; t < NGT; ++t) {
        int ct = __shfl(c4r, t);
        rank += (ct < c) ? 1 : 0;
    }
    if (lane < NGT) {
        out[b * NGT + rank] = c;                    // rows: matched query idx
        out[BS * NGT + b * NGT + rank] = lane;      // cols: corresponding gt idx
    }
}

extern "C" void kernel_launch(void* const* d_in, const int* in_sizes, int n_in,
                              void* d_out, int out_size, void* d_ws, size_t ws_size,
                              hipStream_t stream) {
    const float* prob  = (const float*)d_in[0];
    const int*   label = (const int*)d_in[1];
    const float* heat  = (const float*)d_in[2];
    const float* gt    = (const float*)d_in[3];
    int* out = (int*)d_out;
    float* Cp = (float*)d_ws;   // NCHUNK*BS*NQ*NGT floats = 512 KiB

    cost_kernel<<<dim3(BS * (NQ / QT) * NCHUNK), dim3(256), 0, stream>>>(heat, gt, Cp);
    lsap_kernel<<<dim3(BS), dim3(64), 0, stream>>>(Cp, prob, label, out);
}